// Round 5
// baseline (652.347 us; speedup 1.0000x reference)
//
#include <hip/hip_runtime.h>
#include <cstdint>

#define BATCH   4096
#define IN_DIM  1024
#define D_MODEL 1024
#define BRANCH  16
#define HEIGHT  4
#define N_NODES 69904      // 16 + 256 + 4096 + 65536
#define N_TILES 4369       // internal nodes 0..4368; tile p = cols 16p..16p+15
#define TILE_ELEMS 16384   // 1024 d * 16 k

#define BM 128
#define BN 128
#define BK 16

// ---------------------------------------------------------------------------
// phase1: fused  (a) fp32 GEMM f = X @ W   [blocks 0..255, VALU-bound]
//                (b) Xi repack -> XiP[p][d][k] = Xi[d][16p+k]  [8768 blocks,
//                    DRAM-bound; overlaps the GEMM on free CUs/BW]
// Repack reads 512-col contiguous slabs (2KB granule), LDS-transposes,
// writes per-tile 1KB-contiguous chunks. Complete 16-ary tree: child0 = 16p+1.
// ---------------------------------------------------------------------------
__global__ __launch_bounds__(256) void phase1(const float* __restrict__ X,
                                              const float* __restrict__ W,
                                              const float* __restrict__ Xi,
                                              float* __restrict__ f,
                                              float* __restrict__ XiP) {
    __shared__ float4 smem4[2064];   // 33 KB union (gemm 16.9 KB | repack 33 KB)
    const int bid = blockIdx.x;
    const int t   = threadIdx.x;

    if (bid < 256) {
        // ---------------- GEMM path: BM=BN=128, BK=16, 8x8/thread ----------
        float* As = (float*)smem4;                 // [BK][BM+4]
        float* Bs = (float*)smem4 + BK * (BM + 4); // [BK][BN+4]
#define AS(k, m) As[(k) * (BM + 4) + (m)]
#define BS(k, n) Bs[(k) * (BN + 4) + (n)]
        const int tx = t & 15, ty = t >> 4;
        const int bm = bid >> 3, bn = bid & 7;
        const int arow = t >> 2, ac4 = (t & 3) * 4;
        const int brow = t >> 5, bc4 = (t & 31) * 4;
        const float* Ab = X + (size_t)bm * BM * IN_DIM;
        const float* Bb = W + (size_t)bn * BN;
        float4 ar[2], br[2];
        float acc[8][8] = {};

#define LOAD_TILE(k0)                                                          \
        {                                                                      \
            _Pragma("unroll")                                                  \
            for (int i = 0; i < 2; ++i)                                        \
                ar[i] = *(const float4*)(Ab + (size_t)(arow + 64 * i) * IN_DIM \
                                         + (k0) + ac4);                        \
            _Pragma("unroll")                                                  \
            for (int i = 0; i < 2; ++i)                                        \
                br[i] = *(const float4*)(Bb + (size_t)((k0) + brow + 8 * i) *  \
                                         D_MODEL + bc4);                       \
        }
#define STORE_TILE()                                                           \
        {                                                                      \
            _Pragma("unroll")                                                  \
            for (int i = 0; i < 2; ++i) {                                      \
                AS(ac4 + 0, arow + 64 * i) = ar[i].x;                          \
                AS(ac4 + 1, arow + 64 * i) = ar[i].y;                          \
                AS(ac4 + 2, arow + 64 * i) = ar[i].z;                          \
                AS(ac4 + 3, arow + 64 * i) = ar[i].w;                          \
            }                                                                  \
            _Pragma("unroll")                                                  \
            for (int i = 0; i < 2; ++i)                                        \
                *(float4*)&BS(brow + 8 * i, bc4) = br[i];                      \
        }
#define COMPUTE_TILE()                                                         \
        {                                                                      \
            _Pragma("unroll")                                                  \
            for (int k = 0; k < BK; ++k) {                                     \
                float4 a0 = *(const float4*)&AS(k, ty * 8);                    \
                float4 a1 = *(const float4*)&AS(k, ty * 8 + 4);                \
                float4 b0 = *(const float4*)&BS(k, tx * 4);                    \
                float4 b1 = *(const float4*)&BS(k, tx * 4 + 64);               \
                const float aa[8] = {a0.x, a0.y, a0.z, a0.w,                   \
                                     a1.x, a1.y, a1.z, a1.w};                  \
                const float bb[8] = {b0.x, b0.y, b0.z, b0.w,                   \
                                     b1.x, b1.y, b1.z, b1.w};                  \
                _Pragma("unroll")                                              \
                for (int i = 0; i < 8; ++i)                                    \
                    _Pragma("unroll")                                          \
                    for (int j = 0; j < 8; ++j)                                \
                        acc[i][j] = fmaf(aa[i], bb[j], acc[i][j]);             \
            }                                                                  \
        }

        LOAD_TILE(0);
        STORE_TILE();
        __syncthreads();
        for (int k0 = BK; k0 < IN_DIM; k0 += BK) {
            LOAD_TILE(k0);
            COMPUTE_TILE();
            __syncthreads();
            STORE_TILE();
            __syncthreads();
        }
        COMPUTE_TILE();

        float* Cb = f + (size_t)(bm * BM + ty * 8) * D_MODEL + bn * BN;
#pragma unroll
        for (int i = 0; i < 8; ++i) {
            float4 v0 = {acc[i][0], acc[i][1], acc[i][2], acc[i][3]};
            float4 v1 = {acc[i][4], acc[i][5], acc[i][6], acc[i][7]};
            *(float4*)(Cb + (size_t)i * D_MODEL + tx * 4)      = v0;
            *(float4*)(Cb + (size_t)i * D_MODEL + tx * 4 + 64) = v1;
        }
#undef LOAD_TILE
#undef STORE_TILE
#undef COMPUTE_TILE
#undef AS
#undef BS
    } else {
        // ---------------- repack path: one [16 d x 512 col] slab -----------
        float4 (*S)[129] = (float4(*)[129])smem4;   // [16][129] float4, padded
        const int rid = bid - 256;
        const int pg  = rid >> 6;     // 0..136  (32 tiles each)
        const int dc  = rid & 63;     // 0..63   (16 d-rows each)
        const int c0  = pg << 9;      // column base
        const int d0  = dc << 4;      // d base

#pragma unroll
        for (int j = 0; j < 8; ++j) {
            const int idx = j * 256 + t;     // 0..2047
            const int dr  = idx >> 7;        // 0..15
            const int c4  = idx & 127;       // 0..127
            const int col = c0 + (c4 << 2);
            if (col < N_NODES)
                S[dr][c4] = *(const float4*)(Xi + (size_t)(d0 + dr) * N_NODES
                                             + col);
        }
        __syncthreads();
#pragma unroll
        for (int j = 0; j < 8; ++j) {
            const int idx = j * 256 + t;     // 0..2047
            const int pl  = idx >> 6;        // 0..31
            const int dr  = (idx >> 2) & 15;
            const int kq  = idx & 3;
            const int p   = (pg << 5) + pl;
            if (p < N_TILES) {
                float4 v = S[dr][(pl << 2) + kq];
                *(float4*)(XiP + (size_t)p * TILE_ELEMS +
                           (size_t)(d0 + dr) * 16 + (kq << 2)) = v;
            }
        }
    }
}

// ---------------------------------------------------------------------------
// Tree descent on repacked tiles. One wave per batch row. Each level reads
// tile[cur] = 64 KB FULLY CONTIGUOUS (lane l covers d = 16i + (l>>2),
// k = 4*(l&3)..+3 at float4 offset 256*i + 4*l): 1 KB/instr sequential ->
// near-peak DRAM efficiency (was 64B granules at 280KB stride, 34% peak).
// ---------------------------------------------------------------------------
__global__ __launch_bounds__(256) void descend(const float* __restrict__ f,
                                               const float* __restrict__ XiP,
                                               int* __restrict__ out) {
    __shared__ float fs[4][1024];

    const int t    = threadIdx.x;
    const int lane = t & 63;
    const int w    = t >> 6;
    const int b    = blockIdx.x * 4 + w;

    {   // stage 4 rows of f (coalesced float4)
        const float4* src = (const float4*)(f + (size_t)blockIdx.x * 4 * D_MODEL);
        float4* dst = (float4*)fs;
#pragma unroll
        for (int i = 0; i < 4; ++i) dst[t + 256 * i] = src[t + 256 * i];
    }
    __syncthreads();

    const int q  = lane & 3;    // candidate quad 4q..4q+3
    const int dg = lane >> 2;   // d-group: d = 16i + dg
    const float* frd = fs[w] + dg;

    int cur = 0;
    if (lane == 0) out[(size_t)b * (HEIGHT + 1)] = 0;

    for (int lev = 0; lev < HEIGHT; ++lev) {
        const float* tp = XiP + (size_t)cur * TILE_ELEMS + 4 * lane;

        float4 acc = {0.f, 0.f, 0.f, 0.f};
#pragma unroll 8
        for (int i = 0; i < 64; ++i) {
            float4 x  = *(const float4*)(tp + 256 * i);
            float  fv = frd[16 * i];
            acc.x = fmaf(fv, x.x, acc.x);
            acc.y = fmaf(fv, x.y, acc.y);
            acc.z = fmaf(fv, x.z, acc.z);
            acc.w = fmaf(fv, x.w, acc.w);
        }

        // sum over the 16 d-groups (lanes sharing q)
#pragma unroll
        for (int m = 4; m <= 32; m <<= 1) {
            acc.x += __shfl_xor(acc.x, m);
            acc.y += __shfl_xor(acc.y, m);
            acc.z += __shfl_xor(acc.z, m);
            acc.w += __shfl_xor(acc.w, m);
        }

        // local argmax over this lane's 4 candidates (first-max wins)
        float bv = acc.x; int bc = q * 4;
        if (acc.y > bv) { bv = acc.y; bc = q * 4 + 1; }
        if (acc.z > bv) { bv = acc.z; bc = q * 4 + 2; }
        if (acc.w > bv) { bv = acc.w; bc = q * 4 + 3; }
        // combine across the 4 q-groups; tie -> smaller candidate index
#pragma unroll
        for (int m = 1; m <= 2; m <<= 1) {
            float ov = __shfl_xor(bv, m);
            int   oc = __shfl_xor(bc, m);
            if (ov > bv || (ov == bv && oc < bc)) { bv = ov; bc = oc; }
        }

        cur = 16 * cur + 1 + bc;   // complete tree: child id
        if (lane == 0) out[(size_t)b * (HEIGHT + 1) + lev + 1] = cur;
    }
}

// ---------------------------------------------------------------------------
extern "C" void kernel_launch(void* const* d_in, const int* in_sizes, int n_in,
                              void* d_out, int out_size, void* d_ws, size_t ws_size,
                              hipStream_t stream) {
    const float* X  = (const float*)d_in[0];   // [BATCH, IN_DIM]
    const float* W  = (const float*)d_in[1];   // [IN_DIM, D_MODEL]
    const float* Xi = (const float*)d_in[2];   // [D_MODEL, N_NODES]
    // d_in[3] (children) unneeded: complete 16-ary tree -> child0 = 16*cur+1
    int* out = (int*)d_out;                    // [BATCH, HEIGHT+1] int32

    float* f   = (float*)d_ws;                        // 16 MB
    float* XiP = (float*)d_ws + (size_t)BATCH * D_MODEL;  // 286.3 MB

    const int repack_blocks = 137 * 64;        // 32-tile x 16-d slabs
    phase1<<<256 + repack_blocks, 256, 0, stream>>>(X, W, Xi, f, XiP);

    descend<<<BATCH / 4, 256, 0, stream>>>(f, XiP, out);
}

// Round 7
// 626.469 us; speedup vs baseline: 1.0413x; 1.0413x over previous
//
#include <hip/hip_runtime.h>
#include <cstdint>

#define BATCH   4096
#define IN_DIM  1024
#define D_MODEL 1024
#define BRANCH  16
#define HEIGHT  4
#define N_NODES 69904      // 16 + 256 + 4096 + 65536

#define BM 128
#define BN 128
#define BK 32              // two 16-wide sub-tiles per staging round
#define KSPLIT 2           // blockIdx.z halves of K; partials summed in descend

// ---------------------------------------------------------------------------
// fp32 GEMM, split-K: block (bm,bn,kz) computes f_kz = X[bm,:|kz] @ W[:|kz,bn]
// over K/2 = 512. Grid (32,8,2) = 512 blocks -> 2 blocks/CU (independent
// barrier domains, 2 waves/SIMD). BK=32 halves barrier rate vs round 3
// (2 barriers per ~2048 VALU-cyc). 8x8/thread = 2 flop/LDS-byte.
// Partial sums land in two 16MB buffers; descend adds them while staging.
// ---------------------------------------------------------------------------
__global__ __launch_bounds__(256) void gemm_f32(const float* __restrict__ A,
                                                const float* __restrict__ B,
                                                float* __restrict__ C) {
    __shared__ float As[BK][BM + 4];   // [k][m]
    __shared__ float Bs[BK][BN + 4];   // [k][n]

    const int t  = threadIdx.x;
    const int tx = t & 15;         // 16 col-groups
    const int ty = t >> 4;         // 16 row-groups
    const int bm = blockIdx.x;
    const int bn = blockIdx.y;
    const int kz = blockIdx.z;

    const int arow = t >> 2;             // 0..63
    const int ac4  = (t & 3) * 4;        // 0,4,8,12
    const int brow = t >> 5;             // 0..7
    const int bc4  = (t & 31) * 4;       // 0..124

    const float* Ab = A + (size_t)bm * BM * IN_DIM + (size_t)kz * 512;
    const float* Bb = B + (size_t)kz * 512 * D_MODEL + (size_t)bn * BN;

    float4 ar[2][2], br[2][2];   // [sub-tile s][i]

#define LOAD_TILE(k0)                                                          \
    {                                                                          \
        _Pragma("unroll")                                                      \
        for (int s = 0; s < 2; ++s) {                                          \
            _Pragma("unroll")                                                  \
            for (int i = 0; i < 2; ++i)                                        \
                ar[s][i] = *(const float4*)(Ab + (size_t)(arow + 64 * i) *     \
                                            IN_DIM + (k0) + 16 * s + ac4);     \
            _Pragma("unroll")                                                  \
            for (int i = 0; i < 2; ++i)                                        \
                br[s][i] = *(const float4*)(Bb + (size_t)((k0) + 16 * s +      \
                                            brow + 8 * i) * D_MODEL + bc4);    \
        }                                                                      \
    }

#define STORE_TILE()                                                           \
    {                                                                          \
        _Pragma("unroll")                                                      \
        for (int s = 0; s < 2; ++s) {                                          \
            _Pragma("unroll")                                                  \
            for (int i = 0; i < 2; ++i) {                                      \
                As[16 * s + ac4 + 0][arow + 64 * i] = ar[s][i].x;              \
                As[16 * s + ac4 + 1][arow + 64 * i] = ar[s][i].y;              \
                As[16 * s + ac4 + 2][arow + 64 * i] = ar[s][i].z;              \
                As[16 * s + ac4 + 3][arow + 64 * i] = ar[s][i].w;              \
            }                                                                  \
            _Pragma("unroll")                                                  \
            for (int i = 0; i < 2; ++i)                                        \
                *(float4*)&Bs[16 * s + brow + 8 * i][bc4] = br[s][i];          \
        }                                                                      \
    }

    float acc[8][8] = {};

#define COMPUTE_TILE()                                                         \
    {                                                                          \
        _Pragma("unroll")                                                      \
        for (int k = 0; k < BK; ++k) {                                         \
            float4 a0 = *(const float4*)&As[k][ty * 8];                        \
            float4 a1 = *(const float4*)&As[k][ty * 8 + 4];                    \
            float4 b0 = *(const float4*)&Bs[k][tx * 4];                        \
            float4 b1 = *(const float4*)&Bs[k][tx * 4 + 64];                   \
            const float aa[8] = {a0.x, a0.y, a0.z, a0.w, a1.x, a1.y, a1.z, a1.w};\
            const float bb[8] = {b0.x, b0.y, b0.z, b0.w, b1.x, b1.y, b1.z, b1.w};\
            _Pragma("unroll")                                                  \
            for (int i = 0; i < 8; ++i)                                        \
                _Pragma("unroll")                                              \
                for (int j = 0; j < 8; ++j)                                    \
                    acc[i][j] = fmaf(aa[i], bb[j], acc[i][j]);                 \
        }                                                                      \
    }

    LOAD_TILE(0);
    STORE_TILE();
    __syncthreads();

    for (int k0 = BK; k0 < 512; k0 += BK) {
        LOAD_TILE(k0);       // next tile in regs; compute hides the latency
        COMPUTE_TILE();
        __syncthreads();
        STORE_TILE();
        __syncthreads();
    }
    COMPUTE_TILE();

    float* Cb = C + (size_t)kz * BATCH * D_MODEL +
                (size_t)(bm * BM + ty * 8) * D_MODEL + bn * BN;
#pragma unroll
    for (int i = 0; i < 8; ++i) {
        float4 v0 = {acc[i][0], acc[i][1], acc[i][2], acc[i][3]};
        float4 v1 = {acc[i][4], acc[i][5], acc[i][6], acc[i][7]};
        *(float4*)(Cb + (size_t)i * D_MODEL + tx * 4)      = v0;
        *(float4*)(Cb + (size_t)i * D_MODEL + tx * 4 + 64) = v1;
    }
#undef LOAD_TILE
#undef STORE_TILE
#undef COMPUTE_TILE
}

// ---------------------------------------------------------------------------
// Tree descent (round-3 proven structure). Block = 4 waves = 2 rows x 2
// d-halves; grid 2048 -> 8 blocks/CU. Wave lane = (dg = lane>>2, q = lane&3):
// one float4 covers candidates 4q..4q+3 at d-row (h*512 + 16*i + dg).
// Staging now sums the two split-K partials of f.
// ---------------------------------------------------------------------------
__global__ __launch_bounds__(256, 6) void descend(const float* __restrict__ f,
                                                  const float* __restrict__ Xi,
                                                  int* __restrict__ out) {
    __shared__ float  fs[2][1024];
    __shared__ float4 part[2][2][4];   // [row][half][q]

    const int t    = threadIdx.x;
    const int lane = t & 63;
    const int w    = t >> 6;       // wave 0..3
    const int r    = w >> 1;       // row within block
    const int h    = w & 1;        // d-half
    const int b    = blockIdx.x * 2 + r;

    // stage both f rows, summing the two split-K partials
    {
        const float4* s0 = (const float4*)(f + (size_t)blockIdx.x * 2 * D_MODEL);
        const float4* s1 = s0 + ((size_t)BATCH * D_MODEL) / 4;
        float4* dst = (float4*)fs;
#pragma unroll
        for (int i = 0; i < 2; ++i) {
            float4 a = s0[t + 256 * i];
            float4 c = s1[t + 256 * i];
            float4 v = {a.x + c.x, a.y + c.y, a.z + c.z, a.w + c.w};
            dst[t + 256 * i] = v;
        }
    }

    const int q  = lane & 3;
    const int dg = lane >> 2;
    const float*  frd   = fs[r] + h * 512 + dg;
    const size_t  dbase = (size_t)(h * 512 + dg) * N_NODES;

    if ((w == 0 || w == 2) && lane == 0) out[(size_t)b * (HEIGHT + 1)] = 0;

    __syncthreads();

    int cur = 0;
    for (int lev = 0; lev < HEIGHT; ++lev) {
        const int child0 = 16 * cur + 1;   // complete 16-ary tree
        const float* xp = Xi + dbase + (size_t)(child0 - 1) + q * 4;

        float4 acc = {0.f, 0.f, 0.f, 0.f};
#pragma unroll 8
        for (int i = 0; i < 32; ++i) {
            float4 x  = *(const float4*)xp;
            float  fv = frd[16 * i];
            acc.x = fmaf(fv, x.x, acc.x);
            acc.y = fmaf(fv, x.y, acc.y);
            acc.z = fmaf(fv, x.z, acc.z);
            acc.w = fmaf(fv, x.w, acc.w);
            xp += (size_t)16 * N_NODES;
        }

        // sum the 16 d-groups (lanes sharing q)
#pragma unroll
        for (int m = 4; m <= 32; m <<= 1) {
            acc.x += __shfl_xor(acc.x, m);
            acc.y += __shfl_xor(acc.y, m);
            acc.z += __shfl_xor(acc.z, m);
            acc.w += __shfl_xor(acc.w, m);
        }
        if (lane < 4) part[r][h][lane] = acc;
        __syncthreads();

        // every lane: combine the two d-halves, argmax over 16 candidates
        const float4 s0 = part[r][0][q];
        const float4 s1 = part[r][1][q];
        const float sv[4] = {s0.x + s1.x, s0.y + s1.y, s0.z + s1.z, s0.w + s1.w};
        float bv = sv[0];
        int   bc = q * 4;
#pragma unroll
        for (int j = 1; j < 4; ++j)
            if (sv[j] > bv) { bv = sv[j]; bc = q * 4 + j; }   // first-max wins
#pragma unroll
        for (int m = 1; m <= 2; m <<= 1) {
            float ov = __shfl_xor(bv, m);
            int   oc = __shfl_xor(bc, m);
            if (ov > bv || (ov == bv && oc < bc)) { bv = ov; bc = oc; }
        }

        cur = child0 + bc;                       // uniform across the row's waves
        if (h == 0 && lane == 0)
            out[(size_t)b * (HEIGHT + 1) + lev + 1] = cur;
        __syncthreads();                         // part[] reused next level
    }
}

// ---------------------------------------------------------------------------
extern "C" void kernel_launch(void* const* d_in, const int* in_sizes, int n_in,
                              void* d_out, int out_size, void* d_ws, size_t ws_size,
                              hipStream_t stream) {
    const float* X  = (const float*)d_in[0];   // [BATCH, IN_DIM]
    const float* W  = (const float*)d_in[1];   // [IN_DIM, D_MODEL]
    const float* Xi = (const float*)d_in[2];   // [D_MODEL, N_NODES]
    // d_in[3] (children) unneeded: complete 16-ary tree -> child0 = 16*cur+1
    int* out = (int*)d_out;                    // [BATCH, HEIGHT+1] int32

    float* f = (float*)d_ws;   // two 16MB split-K partials, back to back

    dim3 ggrid(BATCH / BM, D_MODEL / BN, KSPLIT);
    gemm_f32<<<ggrid, 256, 0, stream>>>(X, W, f);

    descend<<<BATCH / 2, 256, 0, stream>>>(f, Xi, out);
}